// Round 3
// baseline (76.554 us; speedup 1.0000x reference)
//
#include <hip/hip_runtime.h>

// VQ-VAE quantizer forward — R13b: software-pipelined persistent blocks.
//   inputs  [B=8, C=64, T=16, H=32, W=32] fp32   (layout: b*C*THW + c*THW + r)
//   codebook[K=512, C=64] fp32
// outputs: q_z [B,C,T,H,W] fp32, vq_loss, commitment_loss (concat flat)
//
// dist(p,k) = ||e_k||^2 - 2*x_p.e_k. Block builds the whole codebook (bf16,
// pre-scaled by -2, XOR-swizzled) + fp32 norms in LDS. MFMA C-init = ||e||^2
// => acc IS the distance. 9-bit code packed into mantissa LSBs => argmin is
// pure f32 min. Loss via ||e-x||^2 = ||x||^2 + d_best.
//
// R13 structure: 256 blocks (1/CU) x 256 threads; each block owns 512
// positions processed as TWO 256-position chunks. All x loads (both chunks)
// issue up front as NT float4 (16 lanes x 16B = 256B full-line segments, R11),
// so chunk1's HBM read streams in under chunk0's scan, and chunk0's NT store
// burst drains under chunk1's scan — read/compute/write overlap that the
// R11/R12 phase-lockstep grids never achieved (R12 post-mortem: 2 in-phase
// blocks/CU gave -2%). Codebook built ONCE per block (was 2x/CU in R12).
// Loss finalize fused: atomic sum + last-block-writes (8B memset initializes
// the accumulators each launch); the separate finalize dispatch is gone.
// R13b: __builtin_nontemporal_load needs an ext-vector type, not the HIP
// float4 class — x loads go through clang ext_vector f32x4.

#define K_CODES 512
#define NCH     64
#define THW     16384
#define NPOS    131072
#define NELEM   8388608
#define NBLK    256

typedef __attribute__((ext_vector_type(8))) short bf16x8;
typedef __attribute__((ext_vector_type(4))) float f32x4;

__device__ __forceinline__ unsigned short f32_bf16(float f) {
    unsigned u = __float_as_uint(f);
    u += 0x7FFFu + ((u >> 16) & 1u);          // round-to-nearest-even
    return (unsigned short)(u >> 16);
}

struct AFrag { bf16x8 a[4][2]; };   // [tile tt][K-half]

// One 256-position chunk: scan 512 codes, argmin, loss partial, q stores.
// Returns the wave-reduced loss partial (valid in lane 0).
__device__ __forceinline__ float chunk_body(
        const AFrag& af, float xn,
        const unsigned char* __restrict__ lds_cb,
        const float* __restrict__ lds_norm,
        int* __restrict__ lds_idx,
        const float* __restrict__ cb,
        float* __restrict__ oq,
        int w, int g, int r15, int tid) {
    float best[4][4];
    #pragma unroll
    for (int tt = 0; tt < 4; ++tt)
        #pragma unroll
        for (int i = 0; i < 4; ++i) best[tt][i] = 3.4e38f;

    const int swz = (r15 & 7) << 4;
    const unsigned char* pb0 = lds_cb + r15 * 128 + ((g * 16) ^ swz);
    const unsigned char* pb1 = lds_cb + r15 * 128 + ((64 + g * 16) ^ swz);
    #pragma unroll
    for (int f = 0; f < 32; ++f) {
        const bf16x8 b0 = *(const bf16x8*)(pb0 + f * 2048);
        const bf16x8 b1 = *(const bf16x8*)(pb1 + f * 2048);
        const float nrm = lds_norm[f * 16 + r15];
        const unsigned code = (unsigned)(f * 16 + r15);   // lane's B-column
        #pragma unroll
        for (int tt = 0; tt < 4; ++tt) {
            f32x4 acc = {nrm, nrm, nrm, nrm};
            acc = __builtin_amdgcn_mfma_f32_16x16x32_bf16(af.a[tt][0], b0, acc, 0, 0, 0);
            acc = __builtin_amdgcn_mfma_f32_16x16x32_bf16(af.a[tt][1], b1, acc, 0, 0, 0);
            #pragma unroll
            for (int i = 0; i < 4; ++i) {   // acc[i]: pos rw+4*(4g+i)+tt
                const float pkv = __uint_as_float(
                    (__float_as_uint(acc[i]) & ~511u) | code);
                best[tt][i] = fminf(best[tt][i], pkv);
            }
        }
    }

    // wave-local argmin (reduce over r15 = code axis)
    float sd = 0.f;
    int   idxs[4][4];
    #pragma unroll
    for (int tt = 0; tt < 4; ++tt) {
        #pragma unroll
        for (int i = 0; i < 4; ++i) {
            float v = best[tt][i];
            #pragma unroll
            for (int off = 8; off; off >>= 1) v = fminf(v, __shfl_xor(v, off));
            sd += v;                                // replicated x16 per group
            idxs[tt][i] = (int)(__float_as_uint(v) & 511u);
        }
    }
    if (r15 == 0) {                   // same-wave RAW only (no barrier needed)
        #pragma unroll
        for (int tt = 0; tt < 4; ++tt)
            #pragma unroll
            for (int i = 0; i < 4; ++i)
                lds_idx[w * 64 + 16 * g + 4 * i + tt] = idxs[tt][i];
    }
    float part = fmaf(sd, 0.0625f, xn);
    #pragma unroll
    for (int off = 32; off; off >>= 1) part += __shfl_down(part, off);

    // epilogue: lane = one position; q from fp32 cb (L2-hot); NT stores
    const int bc = lds_idx[tid];
    const f32x4* crow = (const f32x4*)(cb + (size_t)bc * NCH);
    #pragma unroll
    for (int jj = 0; jj < 16; ++jj) {
        const f32x4 e = crow[jj];
        const size_t c0 = (size_t)(jj * 4) * THW;
        __builtin_nontemporal_store(e[0], oq + c0);
        __builtin_nontemporal_store(e[1], oq + c0 + THW);
        __builtin_nontemporal_store(e[2], oq + c0 + 2 * THW);
        __builtin_nontemporal_store(e[3], oq + c0 + 3 * THW);
    }
    return part;
}

__global__ __launch_bounds__(256, 1) void vq_main(
        const float* __restrict__ x,
        const float* __restrict__ cb,
        float* __restrict__ out,
        float* __restrict__ ws) {
    __shared__ __align__(16) unsigned char lds_cb[65536];   // bf16(-2e), swizzled
    __shared__ __align__(16) float lds_norm[K_CODES];
    __shared__ int   lds_idx[256];
    __shared__ float ws_part[4];

    const int tid  = threadIdx.x;
    const int lane = tid & 63;
    const int w    = tid >> 6;       // wave 0..3
    const int g    = lane >> 4;      // 16-lane group 0..3
    const int r15  = lane & 15;

    const int blk   = blockIdx.x;
    const int b     = blk >> 5;                 // batch (32 blocks per batch)
    const int rbase = (blk & 31) << 9;          // 512 positions per block
    const float* xb = x + (size_t)b * (NCH * THW);

    // ---- x loads, BOTH chunks up front: NT f32x4, 256B contiguous segments.
    // lane(g,r15) gets positions {rw+4*r15+tt, tt=0..3} of channel kf*32+g*8+j
    f32x4 xv[2][2][8];
    #pragma unroll
    for (int c = 0; c < 2; ++c)
        #pragma unroll
        for (int kf = 0; kf < 2; ++kf)
            #pragma unroll
            for (int j = 0; j < 8; ++j)
                xv[c][kf][j] = __builtin_nontemporal_load(
                    (const f32x4*)(xb + (size_t)(kf * 32 + g * 8 + j) * THW
                                      + rbase + c * 256 + w * 64 + 4 * r15));

    // ---- build FULL codebook in LDS once per block (16 rounds; overlaps x
    // latency): thread t owns logical 16B chunk j8=t&7 of row r=(t>>3)+32*rr,
    // stored at physical chunk j8^(r&7) => swizzled, matches scan map. ----
    #pragma unroll
    for (int rr = 0; rr < 16; ++rr) {
        const int r  = (tid >> 3) + (rr << 5);
        const int j8 = tid & 7;
        const f32x4* cr = (const f32x4*)(cb + r * NCH + j8 * 8);
        const f32x4 e0 = cr[0];
        const f32x4 e1 = cr[1];
        float s = e0[0] * e0[0];
        s = fmaf(e0[1], e0[1], s); s = fmaf(e0[2], e0[2], s); s = fmaf(e0[3], e0[3], s);
        s = fmaf(e1[0], e1[0], s); s = fmaf(e1[1], e1[1], s); s = fmaf(e1[2], e1[2], s);
        s = fmaf(e1[3], e1[3], s);
        s += __shfl_xor(s, 1); s += __shfl_xor(s, 2); s += __shfl_xor(s, 4);
        if (j8 == 0) lds_norm[r] = s;          // ||e_r||^2 (unscaled)
        bf16x8 pk;
        pk[0] = (short)f32_bf16(-2.f * e0[0]);
        pk[1] = (short)f32_bf16(-2.f * e0[1]);
        pk[2] = (short)f32_bf16(-2.f * e0[2]);
        pk[3] = (short)f32_bf16(-2.f * e0[3]);
        pk[4] = (short)f32_bf16(-2.f * e1[0]);
        pk[5] = (short)f32_bf16(-2.f * e1[1]);
        pk[6] = (short)f32_bf16(-2.f * e1[2]);
        pk[7] = (short)f32_bf16(-2.f * e1[3]);
        *(bf16x8*)(lds_cb + r * 128 + ((j8 ^ (r & 7)) * 16)) = pk;
    }

    // ---- convert chunk0 to bf16 A-frags + ||x||^2 partial (before barrier:
    // hides under other waves' build) ----
    AFrag af0;
    float xn0 = 0.f;
    #pragma unroll
    for (int kf = 0; kf < 2; ++kf)
        #pragma unroll
        for (int j = 0; j < 8; ++j) {
            const f32x4 v = xv[0][kf][j];
            xn0 = fmaf(v[0], v[0], xn0);
            xn0 = fmaf(v[1], v[1], xn0);
            xn0 = fmaf(v[2], v[2], xn0);
            xn0 = fmaf(v[3], v[3], xn0);
            af0.a[0][kf][j] = (short)f32_bf16(v[0]);
            af0.a[1][kf][j] = (short)f32_bf16(v[1]);
            af0.a[2][kf][j] = (short)f32_bf16(v[2]);
            af0.a[3][kf][j] = (short)f32_bf16(v[3]);
        }

    __syncthreads();   // codebook + norms resident

    float* oq0 = out + (size_t)b * (NCH * THW) + rbase + tid;
    float psum = chunk_body(af0, xn0, lds_cb, lds_norm, lds_idx, cb,
                            oq0, w, g, r15, tid);

    // ---- chunk1: xv[1] has long since arrived (streamed under scan0) ----
    AFrag af1;
    float xn1 = 0.f;
    #pragma unroll
    for (int kf = 0; kf < 2; ++kf)
        #pragma unroll
        for (int j = 0; j < 8; ++j) {
            const f32x4 v = xv[1][kf][j];
            xn1 = fmaf(v[0], v[0], xn1);
            xn1 = fmaf(v[1], v[1], xn1);
            xn1 = fmaf(v[2], v[2], xn1);
            xn1 = fmaf(v[3], v[3], xn1);
            af1.a[0][kf][j] = (short)f32_bf16(v[0]);
            af1.a[1][kf][j] = (short)f32_bf16(v[1]);
            af1.a[2][kf][j] = (short)f32_bf16(v[2]);
            af1.a[3][kf][j] = (short)f32_bf16(v[3]);
        }
    psum += chunk_body(af1, xn1, lds_cb, lds_norm, lds_idx, cb,
                       oq0 + 256, w, g, r15, tid);

    // ---- fused loss finalize: block sum -> global atomic; last block writes.
    if (lane == 0) ws_part[w] = psum;
    __syncthreads();
    if (tid == 0) {
        const float bsum = (ws_part[0] + ws_part[1]) + (ws_part[2] + ws_part[3]);
        float*    gsum = ws;
        unsigned* gcnt = (unsigned*)(ws + 1);
        atomicAdd(gsum, bsum);
        __threadfence();
        const unsigned old = atomicAdd(gcnt, 1u);
        if ((old % NBLK) == NBLK - 1) {     // last arrival (mod: rocprof replay safe)
            __threadfence();
            const float total  = atomicAdd(gsum, 0.f);   // RMW => sees all adds
            const float commit = total * (1.0f / (float)NELEM);
            out[NELEM]     = 0.25f * commit;   // vq_loss
            out[NELEM + 1] = commit;           // commitment_loss
        }
    }
}

extern "C" void kernel_launch(void* const* d_in, const int* in_sizes, int n_in,
                              void* d_out, int out_size, void* d_ws, size_t ws_size,
                              hipStream_t stream) {
    const float* x  = (const float*)d_in[0];
    const float* cb = (const float*)d_in[1];
    float* out      = (float*)d_out;
    float* ws       = (float*)d_ws;        // [0]=loss sum (f32), [1]=arrival cnt

    (void)hipMemsetAsync(d_ws, 0, 8, stream);   // graph-capturable memset node
    vq_main<<<NBLK, 256, 0, stream>>>(x, cb, out, ws);
}

// Round 4
// 38.839 us; speedup vs baseline: 1.9710x; 1.9710x over previous
//
#include <hip/hip_runtime.h>

// VQ-VAE quantizer forward — R14: 16 waves/CU via VGPR<=128 discipline.
//   inputs  [B=8, C=64, T=16, H=32, W=32] fp32   (layout: b*C*THW + c*THW + r)
//   codebook[K=512, C=64] fp32
// outputs: q_z [B,C,T,H,W] fp32, vq_loss, commitment_loss (concat flat)
//
// dist(p,k) = ||e_k||^2 - 2*x_p.e_k. Block builds the whole codebook (bf16,
// pre-scaled by -2, XOR-swizzled) + fp32 norms in LDS. MFMA C-init = ||e||^2
// => acc IS the distance. 9-bit code packed into mantissa LSBs => argmin is
// pure f32 min. Loss via ||e-x||^2 = ||x||^2 + d_best.
//
// R13b post-mortem: up-front double-chunk loads -> VGPR 256 + scratch spills
// (WRITE 85.5 MB vs 33.6 ideal = spill traffic), 4 waves/CU, 76 us. R11/R12
// both ran 8 waves/CU (2/SIMD) = 27 us; the stall gap vs the ~11 us overlap
// bound is latency exposure. LDS (68.6 KB) already allows 2x512-thr blocks/CU
// (137 <= 160 KB); the blocker was VGPR > 128.
//
// R14: R11 block structure (512 thr = 8 waves, 64 pos/wave, 512 pos/block,
// 256 blocks), but __launch_bounds__(512,4) => VGPR cap 128 => 2 blocks/CU,
// 16 waves/CU, 4 waves/SIMD. Register discipline: x is loaded and converted
// in TWO kf-halves interleaved with a split codebook build, so only 8 float4
// of x are live at once (peak ~100 VGPR vs R11's ~140+). NT x loads (read-
// once; keep L2/L3 for cb). NT q stores (R4: exact bytes). Loss finalize
// fused via global atomic + last-block-writes (R13-proven; no 2nd dispatch).

#define K_CODES 512
#define NCH     64
#define THW     16384
#define NPOS    131072
#define NELEM   8388608
#define NBLK    256

typedef __attribute__((ext_vector_type(8))) short bf16x8;
typedef __attribute__((ext_vector_type(4))) float f32x4;

__device__ __forceinline__ unsigned short f32_bf16(float f) {
    unsigned u = __float_as_uint(f);
    u += 0x7FFFu + ((u >> 16) & 1u);          // round-to-nearest-even
    return (unsigned short)(u >> 16);
}

__global__ __launch_bounds__(512, 4) void vq_main(
        const float* __restrict__ x,
        const float* __restrict__ cb,
        float* __restrict__ out,
        float* __restrict__ ws) {
    __shared__ __align__(16) unsigned char lds_cb[65536];   // bf16(-2e), swizzled
    __shared__ __align__(16) float lds_norm[K_CODES];
    __shared__ int   lds_idx[512];
    __shared__ float ws_part[8];

    const int tid  = threadIdx.x;
    const int lane = tid & 63;
    const int w    = tid >> 6;       // wave 0..7
    const int g    = lane >> 4;      // 16-lane group 0..3
    const int r15  = lane & 15;

    const int blk  = blockIdx.x;
    const int b    = blk >> 5;                 // batch (32 blocks per batch)
    const int rblk = (blk & 31) << 9;          // 512 positions per block
    const int rw   = rblk + w * 64;            // wave's first position
    const float* xb = x + (size_t)b * (NCH * THW);

    bf16x8 af[4][2];     // A-frags [tile tt][K-half]
    float  xn = 0.f;     // ||x||^2 partial

    // ================= kf = 0 half =================
    // x loads: NT float4; 16 lanes x 16B = 256B full-line segments.
    // lane(g,r15) gets positions {rw+4*r15+tt, tt=0..3} of channel g*8+j
    f32x4 xv[8];
    #pragma unroll
    for (int j = 0; j < 8; ++j)
        xv[j] = __builtin_nontemporal_load(
            (const f32x4*)(xb + (size_t)(g * 8 + j) * THW + rw + 4 * r15));

    // build codebook rows 0..255 in LDS (hides the kf=0 load latency):
    // thread t owns logical 16B chunk j8=t&7 of code row r=(t>>3)+64*rr,
    // stored at physical chunk j8^(r&7) => swizzled, matches scan map.
    #pragma unroll
    for (int rr = 0; rr < 4; ++rr) {
        const int r  = (tid >> 3) + (rr << 6);
        const int j8 = tid & 7;
        const f32x4* cr = (const f32x4*)(cb + r * NCH + j8 * 8);
        const f32x4 e0 = cr[0];
        const f32x4 e1 = cr[1];
        float s = e0[0] * e0[0];
        s = fmaf(e0[1], e0[1], s); s = fmaf(e0[2], e0[2], s); s = fmaf(e0[3], e0[3], s);
        s = fmaf(e1[0], e1[0], s); s = fmaf(e1[1], e1[1], s); s = fmaf(e1[2], e1[2], s);
        s = fmaf(e1[3], e1[3], s);
        s += __shfl_xor(s, 1); s += __shfl_xor(s, 2); s += __shfl_xor(s, 4);
        if (j8 == 0) lds_norm[r] = s;          // ||e_r||^2 (unscaled)
        bf16x8 pk;
        pk[0] = (short)f32_bf16(-2.f * e0[0]);
        pk[1] = (short)f32_bf16(-2.f * e0[1]);
        pk[2] = (short)f32_bf16(-2.f * e0[2]);
        pk[3] = (short)f32_bf16(-2.f * e0[3]);
        pk[4] = (short)f32_bf16(-2.f * e1[0]);
        pk[5] = (short)f32_bf16(-2.f * e1[1]);
        pk[6] = (short)f32_bf16(-2.f * e1[2]);
        pk[7] = (short)f32_bf16(-2.f * e1[3]);
        *(bf16x8*)(lds_cb + r * 128 + ((j8 ^ (r & 7)) * 16)) = pk;
    }

    // convert kf=0 (xv dies here => registers recycled for kf=1)
    #pragma unroll
    for (int j = 0; j < 8; ++j) {
        const f32x4 v = xv[j];
        xn = fmaf(v[0], v[0], xn);
        xn = fmaf(v[1], v[1], xn);
        xn = fmaf(v[2], v[2], xn);
        xn = fmaf(v[3], v[3], xn);
        af[0][0][j] = (short)f32_bf16(v[0]);
        af[1][0][j] = (short)f32_bf16(v[1]);
        af[2][0][j] = (short)f32_bf16(v[2]);
        af[3][0][j] = (short)f32_bf16(v[3]);
    }

    // ================= kf = 1 half =================
    #pragma unroll
    for (int j = 0; j < 8; ++j)
        xv[j] = __builtin_nontemporal_load(
            (const f32x4*)(xb + (size_t)(32 + g * 8 + j) * THW + rw + 4 * r15));

    // build codebook rows 256..511
    #pragma unroll
    for (int rr = 4; rr < 8; ++rr) {
        const int r  = (tid >> 3) + (rr << 6);
        const int j8 = tid & 7;
        const f32x4* cr = (const f32x4*)(cb + r * NCH + j8 * 8);
        const f32x4 e0 = cr[0];
        const f32x4 e1 = cr[1];
        float s = e0[0] * e0[0];
        s = fmaf(e0[1], e0[1], s); s = fmaf(e0[2], e0[2], s); s = fmaf(e0[3], e0[3], s);
        s = fmaf(e1[0], e1[0], s); s = fmaf(e1[1], e1[1], s); s = fmaf(e1[2], e1[2], s);
        s = fmaf(e1[3], e1[3], s);
        s += __shfl_xor(s, 1); s += __shfl_xor(s, 2); s += __shfl_xor(s, 4);
        if (j8 == 0) lds_norm[r] = s;
        bf16x8 pk;
        pk[0] = (short)f32_bf16(-2.f * e0[0]);
        pk[1] = (short)f32_bf16(-2.f * e0[1]);
        pk[2] = (short)f32_bf16(-2.f * e0[2]);
        pk[3] = (short)f32_bf16(-2.f * e0[3]);
        pk[4] = (short)f32_bf16(-2.f * e1[0]);
        pk[5] = (short)f32_bf16(-2.f * e1[1]);
        pk[6] = (short)f32_bf16(-2.f * e1[2]);
        pk[7] = (short)f32_bf16(-2.f * e1[3]);
        *(bf16x8*)(lds_cb + r * 128 + ((j8 ^ (r & 7)) * 16)) = pk;
    }

    // convert kf=1
    #pragma unroll
    for (int j = 0; j < 8; ++j) {
        const f32x4 v = xv[j];
        xn = fmaf(v[0], v[0], xn);
        xn = fmaf(v[1], v[1], xn);
        xn = fmaf(v[2], v[2], xn);
        xn = fmaf(v[3], v[3], xn);
        af[0][1][j] = (short)f32_bf16(v[0]);
        af[1][1][j] = (short)f32_bf16(v[1]);
        af[2][1][j] = (short)f32_bf16(v[2]);
        af[3][1][j] = (short)f32_bf16(v[3]);
    }

    __syncthreads();   // codebook + norms resident

    // ---- scan all 512 codes ----
    float best[4][4];
    #pragma unroll
    for (int tt = 0; tt < 4; ++tt)
        #pragma unroll
        for (int i = 0; i < 4; ++i) best[tt][i] = 3.4e38f;

    const int swz = (r15 & 7) << 4;
    const unsigned char* pb0 = lds_cb + r15 * 128 + ((g * 16) ^ swz);
    const unsigned char* pb1 = lds_cb + r15 * 128 + ((64 + g * 16) ^ swz);
    #pragma unroll
    for (int f = 0; f < 32; ++f) {
        const bf16x8 b0 = *(const bf16x8*)(pb0 + f * 2048);
        const bf16x8 b1 = *(const bf16x8*)(pb1 + f * 2048);
        const float nrm = lds_norm[f * 16 + r15];
        const unsigned code = (unsigned)(f * 16 + r15);   // lane's B-column
        #pragma unroll
        for (int tt = 0; tt < 4; ++tt) {
            f32x4 acc = {nrm, nrm, nrm, nrm};
            acc = __builtin_amdgcn_mfma_f32_16x16x32_bf16(af[tt][0], b0, acc, 0, 0, 0);
            acc = __builtin_amdgcn_mfma_f32_16x16x32_bf16(af[tt][1], b1, acc, 0, 0, 0);
            #pragma unroll
            for (int i = 0; i < 4; ++i) {   // acc[i]: pos rw+4*(4g+i)+tt
                const float pkv = __uint_as_float(
                    (__float_as_uint(acc[i]) & ~511u) | code);
                best[tt][i] = fminf(best[tt][i], pkv);
            }
        }
    }

    // ---- wave-local argmin (reduce over r15 = code axis) ----
    float sd = 0.f;
    int   idxs[4][4];
    #pragma unroll
    for (int tt = 0; tt < 4; ++tt) {
        #pragma unroll
        for (int i = 0; i < 4; ++i) {
            float v = best[tt][i];
            #pragma unroll
            for (int off = 8; off; off >>= 1) v = fminf(v, __shfl_xor(v, off));
            sd += v;                                // replicated x16 per group
            idxs[tt][i] = (int)(__float_as_uint(v) & 511u);
        }
    }
    if (r15 == 0) {                   // same-wave RAW only (no barrier needed)
        #pragma unroll
        for (int tt = 0; tt < 4; ++tt)
            #pragma unroll
            for (int i = 0; i < 4; ++i)
                lds_idx[w * 64 + 16 * g + 4 * i + tt] = idxs[tt][i];
    }
    // per-wave loss partial: sum(||x||^2) + sum(d_best)/16
    float part = fmaf(sd, 0.0625f, xn);
    #pragma unroll
    for (int off = 32; off; off >>= 1) part += __shfl_down(part, off);
    if (lane == 0) ws_part[w] = part;

    // ---- epilogue: lane = one position; q from fp32 cb (L2-hot); NT stores
    const int bc = lds_idx[tid];
    float* oq = out + (size_t)b * (NCH * THW) + (rblk + tid);
    const f32x4* crow = (const f32x4*)(cb + (size_t)bc * NCH);
    #pragma unroll
    for (int jj = 0; jj < 16; ++jj) {
        const f32x4 e = crow[jj];
        const size_t c0 = (size_t)(jj * 4) * THW;
        __builtin_nontemporal_store(e[0], oq + c0);
        __builtin_nontemporal_store(e[1], oq + c0 + THW);
        __builtin_nontemporal_store(e[2], oq + c0 + 2 * THW);
        __builtin_nontemporal_store(e[3], oq + c0 + 3 * THW);
    }

    // ---- fused loss finalize: block sum -> global atomic; last block writes.
    __syncthreads();
    if (tid == 0) {
        float bsum = 0.f;
        #pragma unroll
        for (int i = 0; i < 8; ++i) bsum += ws_part[i];
        float*    gsum = ws;
        unsigned* gcnt = (unsigned*)(ws + 1);
        atomicAdd(gsum, bsum);
        __threadfence();
        const unsigned old = atomicAdd(gcnt, 1u);
        if ((old % NBLK) == NBLK - 1) {     // last arrival (mod: rocprof replay safe)
            __threadfence();
            const float total  = atomicAdd(gsum, 0.f);   // RMW => sees all adds
            const float commit = total * (1.0f / (float)NELEM);
            out[NELEM]     = 0.25f * commit;   // vq_loss
            out[NELEM + 1] = commit;           // commitment_loss
        }
    }
}

extern "C" void kernel_launch(void* const* d_in, const int* in_sizes, int n_in,
                              void* d_out, int out_size, void* d_ws, size_t ws_size,
                              hipStream_t stream) {
    const float* x  = (const float*)d_in[0];
    const float* cb = (const float*)d_in[1];
    float* out      = (float*)d_out;
    float* ws       = (float*)d_ws;        // [0]=loss sum (f32), [1]=arrival cnt

    (void)hipMemsetAsync(d_ws, 0, 8, stream);   // graph-capturable memset node
    vq_main<<<NBLK, 512, 0, stream>>>(x, cb, out, ws);
}